// Round 1
// baseline (550.017 us; speedup 1.0000x reference)
//
#include <hip/hip_runtime.h>

typedef __attribute__((ext_vector_type(8))) short short8;
typedef __attribute__((ext_vector_type(4))) float f32x4;

#define BB 2
#define SS 2048
#define HH 16
#define NOPE_D 128
#define ROPE_D 64
#define VDIM 128
#define QD 192    // NOPE+ROPE
#define KVD 256   // NOPE+VD
#define SCALE_F 0.07216878364870323f  // 1/sqrt(192)

__device__ __forceinline__ unsigned short f2bf(float f) {
    unsigned int x = __builtin_bit_cast(unsigned int, f);
    unsigned int r = (x + 0x7fffu + ((x >> 16) & 1u)) >> 16;
    return (unsigned short)r;
}
__device__ __forceinline__ float bf2f(unsigned short u) {
    unsigned int x = ((unsigned int)u) << 16;
    return __builtin_bit_cast(float, x);
}

// C[m][n] = sum_k A[m][k] * B[n][k]; A: MxK f32, B: NxK f32, C: MxN bf16(ushort)
// M,N,K multiples of 64. Block 256 (4 waves), tile 64x64, BK=64.
__global__ __launch_bounds__(256) void gemm_bt_f32_bf16(
    const float* __restrict__ A, const float* __restrict__ B,
    unsigned short* __restrict__ C, int M, int N, int K)
{
    __shared__ unsigned short As[64][72];
    __shared__ unsigned short Bs[64][72];
    const int t = threadIdx.x;
    const int w = t >> 6, lane = t & 63, n = lane & 15, quad = lane >> 4;
    const int bm = blockIdx.y * 64, bn = blockIdx.x * 64;

    f32x4 acc[4] = {};

    for (int k0 = 0; k0 < K; k0 += 64) {
        __syncthreads();
        for (int i = 0; i < 4; i++) {
            int f = t + i * 256;            // 1024 float4 chunks total (A) and (B)
            int r = f >> 4, c4 = (f & 15) * 4;
            float4 av = *(const float4*)(A + (size_t)(bm + r) * K + k0 + c4);
            float4 bv = *(const float4*)(B + (size_t)(bn + r) * K + k0 + c4);
            ushort4 au = { f2bf(av.x), f2bf(av.y), f2bf(av.z), f2bf(av.w) };
            ushort4 bu = { f2bf(bv.x), f2bf(bv.y), f2bf(bv.z), f2bf(bv.w) };
            *(ushort4*)&As[r][c4] = au;
            *(ushort4*)&Bs[r][c4] = bu;
        }
        __syncthreads();
        for (int ks = 0; ks < 2; ks++) {
            short8 af = *(const short8*)&As[w * 16 + n][ks * 32 + quad * 8];
            for (int nt = 0; nt < 4; nt++) {
                short8 bf = *(const short8*)&Bs[nt * 16 + n][ks * 32 + quad * 8];
                acc[nt] = __builtin_amdgcn_mfma_f32_16x16x32_bf16(af, bf, acc[nt], 0, 0, 0);
            }
        }
    }
    for (int nt = 0; nt < 4; nt++)
        for (int r = 0; r < 4; r++)
            C[(size_t)(bm + w * 16 + quad * 4 + r) * N + bn + nt * 16 + n] = f2bf(acc[nt][r]);
}

// In-place RoPE on q_pe: q buffer is (4096, H*192) bf16; pe at cols h*192+128..191
__global__ __launch_bounds__(256) void rope_q_kernel(unsigned short* __restrict__ q,
    const float* __restrict__ cs, const float* __restrict__ sn)
{
    int idx = blockIdx.x * 256 + threadIdx.x;  // 4096*16*32
    int i = idx & 31;
    int h = (idx >> 5) & 15;
    int row = idx >> 9;
    size_t base = (size_t)row * (HH * QD) + h * QD + NOPE_D;
    float x1 = bf2f(q[base + i]);
    float x2 = bf2f(q[base + 32 + i]);
    float c1 = cs[row * 64 + i],      s1 = sn[row * 64 + i];
    float c2 = cs[row * 64 + 32 + i], s2 = sn[row * 64 + 32 + i];
    q[base + i]      = f2bf(x1 * c1 - x2 * s1);
    q[base + 32 + i] = f2bf(x2 * c2 + x1 * s2);
}

// k_pe = rope(PE): (4096,64) f32 -> bf16
__global__ __launch_bounds__(256) void rope_k_kernel(const float* __restrict__ pe,
    const float* __restrict__ cs, const float* __restrict__ sn,
    unsigned short* __restrict__ kpe)
{
    int idx = blockIdx.x * 256 + threadIdx.x;  // 4096*32
    int i = idx & 31;
    int row = idx >> 5;
    float x1 = pe[row * 64 + i], x2 = pe[row * 64 + 32 + i];
    float c1 = cs[row * 64 + i],      s1 = sn[row * 64 + i];
    float c2 = cs[row * 64 + 32 + i], s2 = sn[row * 64 + 32 + i];
    kpe[row * 64 + i]      = f2bf(x1 * c1 - x2 * s1);
    kpe[row * 64 + 32 + i] = f2bf(x2 * c2 + x1 * s2);
}

// Flash attention, causal. Grid (32, 16, 2) = (qtile, h, b), block 256 (4 waves).
// BQ=64 (16 rows/wave), BK=64. Head dim: 128 nope + 64 rope = 192 (6 k-steps). V: 128.
__global__ __launch_bounds__(256) void attn_kernel(
    const unsigned short* __restrict__ qbuf,   // (4096, 3072) bf16
    const unsigned short* __restrict__ kvbuf,  // (4096, 4096) bf16
    const unsigned short* __restrict__ kpe,    // (4096, 64) bf16
    float* __restrict__ out)                   // (B,S,H,128) f32
{
    const int qt = (int)gridDim.x - 1 - (int)blockIdx.x;  // long blocks first
    const int h = blockIdx.y, b = blockIdx.z;
    const int t = threadIdx.x;
    const int w = t >> 6, lane = t & 63, n = lane & 15, quad = lane >> 4;

    __shared__ unsigned short Ks[64][200];   // keys x (128 nope + 64 pe), pad->200
    __shared__ unsigned short Vt[128][72];   // vdim x keys, pad->72
    __shared__ unsigned short Ps[4][16][72]; // per-wave P tile 16x64, pad->72

    // Q fragments: wave w owns q rows qt*64 + w*16 + m (m = lane&15)
    short8 qf[6];
    {
        size_t grow = (size_t)(b * SS + qt * 64 + w * 16 + n);
        const unsigned short* qp = qbuf + grow * (HH * QD) + h * QD + quad * 8;
        for (int ks = 0; ks < 6; ks++) qf[ks] = *(const short8*)(qp + ks * 32);
    }

    f32x4 O[8] = {};
    float m_i[4], l_i[4];
    for (int r = 0; r < 4; r++) { m_i[r] = -INFINITY; l_i[r] = 0.f; }

    for (int kt = 0; kt <= qt; kt++) {
        __syncthreads();
        // stage K tile: 64 keys x 24 chunks of 8 bf16 (16 from k_nope, 8 from k_pe)
        for (int i = 0; i < 6; i++) {
            int u = t + i * 256;             // 1536 chunks
            int key = u / 24, c8 = u % 24;
            size_t krow = (size_t)(b * SS + kt * 64 + key);
            const unsigned short* src = (c8 < 16)
                ? (kvbuf + krow * (HH * KVD) + h * KVD + c8 * 8)
                : (kpe + krow * 64 + (c8 - 16) * 8);
            *(short8*)&Ks[key][c8 * 8] = *(const short8*)src;
        }
        // stage V transposed: thread t handles key=t&63, chunk cg=t>>6
        {
            int key = t & 63, cg = t >> 6;
            size_t krow = (size_t)(b * SS + kt * 64 + key);
            const unsigned short* vp = kvbuf + krow * (HH * KVD) + h * KVD + NOPE_D;
            for (int p = 0; p < 4; p++) {
                int vb = cg * 8 + p * 32;
                short8 v = *(const short8*)(vp + vb);
                for (int i2 = 0; i2 < 8; i2++)
                    Vt[vb + i2][key] = (unsigned short)v[i2];
            }
        }
        __syncthreads();

        // QK^T: scores 16x64 per wave
        f32x4 Sg[4];
        for (int nt = 0; nt < 4; nt++) {
            f32x4 a = {};
            for (int ks = 0; ks < 6; ks++) {
                short8 bfr = *(const short8*)&Ks[nt * 16 + n][ks * 32 + quad * 8];
                a = __builtin_amdgcn_mfma_f32_16x16x32_bf16(qf[ks], bfr, a, 0, 0, 0);
            }
            Sg[nt] = a;
        }
        // scale + causal mask (diagonal tile only)
        const bool diag = (kt == qt);
        for (int nt = 0; nt < 4; nt++)
            for (int r = 0; r < 4; r++) {
                float s = Sg[nt][r] * SCALE_F;
                if (diag) {
                    int col = nt * 16 + n, row = w * 16 + quad * 4 + r;
                    if (col > row) s = -INFINITY;
                }
                Sg[nt][r] = s;
            }
        // online softmax per row (row = quad*4+r; reduce over 16 lanes of quad)
        float alpha[4];
        for (int r = 0; r < 4; r++) {
            float mx = fmaxf(fmaxf(Sg[0][r], Sg[1][r]), fmaxf(Sg[2][r], Sg[3][r]));
            for (int off = 1; off < 16; off <<= 1) mx = fmaxf(mx, __shfl_xor(mx, off, 64));
            float mnew = fmaxf(m_i[r], mx);
            alpha[r] = __expf(m_i[r] - mnew);
            m_i[r] = mnew;
            float rs = 0.f;
            for (int nt = 0; nt < 4; nt++) {
                float p = __expf(Sg[nt][r] - mnew);
                Sg[nt][r] = p;
                rs += p;
            }
            for (int off = 1; off < 16; off <<= 1) rs += __shfl_xor(rs, off, 64);
            l_i[r] = l_i[r] * alpha[r] + rs;
        }
        // P -> LDS (per-wave region; wave-internal DS ordering makes read-after-write safe)
        for (int nt = 0; nt < 4; nt++)
            for (int r = 0; r < 4; r++)
                Ps[w][quad * 4 + r][nt * 16 + n] = f2bf(Sg[nt][r]);
        // rescale O
        for (int v8 = 0; v8 < 8; v8++)
            for (int r = 0; r < 4; r++) O[v8][r] *= alpha[r];
        // PV: O[16 x 128] += P[16 x 64] * V[64 x 128]
        for (int ks = 0; ks < 2; ks++) {
            short8 pa = *(const short8*)&Ps[w][n][ks * 32 + quad * 8];
            for (int v8 = 0; v8 < 8; v8++) {
                short8 vb = *(const short8*)&Vt[v8 * 16 + n][ks * 32 + quad * 8];
                O[v8] = __builtin_amdgcn_mfma_f32_16x16x32_bf16(pa, vb, O[v8], 0, 0, 0);
            }
        }
    }

    // epilogue: out[b][q][h][vd]
    for (int r = 0; r < 4; r++) {
        float inv = 1.f / l_i[r];
        size_t qrow = (size_t)(b * SS + qt * 64 + w * 16 + quad * 4 + r);
        float* op = out + (qrow * HH + h) * VDIM;
        for (int v8 = 0; v8 < 8; v8++)
            op[v8 * 16 + n] = O[v8][r] * inv;
    }
}

extern "C" void kernel_launch(void* const* d_in, const int* in_sizes, int n_in,
                              void* d_out, int out_size, void* d_ws, size_t ws_size,
                              hipStream_t stream) {
    const float* Q    = (const float*)d_in[0];
    const float* KV   = (const float*)d_in[1];
    const float* PE   = (const float*)d_in[2];
    const float* WUQ  = (const float*)d_in[3];
    const float* WUKV = (const float*)d_in[4];
    const float* cosp = (const float*)d_in[5];
    const float* sinp = (const float*)d_in[6];
    // d_in[7] = mask: causality computed inline, not read
    float* out = (float*)d_out;

    unsigned short* qbuf = (unsigned short*)d_ws;                 // 4096*3072 bf16
    unsigned short* kvb  = qbuf + (size_t)4096 * 3072;            // 4096*4096 bf16
    unsigned short* kpe  = kvb + (size_t)4096 * 4096;             // 4096*64 bf16

    // q = Q @ WUQ^T : M=4096, N=3072, K=1536
    gemm_bt_f32_bf16<<<dim3(3072 / 64, 4096 / 64), 256, 0, stream>>>(Q, WUQ, qbuf, 4096, 3072, 1536);
    // kv = KV @ WUKV^T : M=4096, N=4096, K=512
    gemm_bt_f32_bf16<<<dim3(4096 / 64, 4096 / 64), 256, 0, stream>>>(KV, WUKV, kvb, 4096, 4096, 512);
    // rope q_pe in place
    rope_q_kernel<<<(4096 * 16 * 32) / 256, 256, 0, stream>>>(qbuf, cosp, sinp);
    // rope k_pe
    rope_k_kernel<<<(4096 * 32) / 256, 256, 0, stream>>>(PE, cosp, sinp, kpe);
    // attention
    attn_kernel<<<dim3(SS / 64, HH, BB), 256, 0, stream>>>(qbuf, kvb, kpe, out);
}

// Round 2
// 403.339 us; speedup vs baseline: 1.3637x; 1.3637x over previous
//
#include <hip/hip_runtime.h>

typedef __attribute__((ext_vector_type(8))) short short8;
typedef __attribute__((ext_vector_type(4))) float f32x4;

#define SS 2048
#define HH 16
#define NOPE_D 128
#define ROPE_D 64
#define VDIM 128
#define QD 192
#define SCALE_F 0.07216878364870323f       // 1/sqrt(192)
#define LOG2E 1.4426950408889634f

__device__ __forceinline__ unsigned short f2bf(float f) {
    unsigned int x = __builtin_bit_cast(unsigned int, f);
    unsigned int r = (x + 0x7fffu + ((x >> 16) & 1u)) >> 16;
    return (unsigned short)r;
}
__device__ __forceinline__ float bf2f(unsigned short u) {
    unsigned int x = ((unsigned int)u) << 16;
    return __builtin_bit_cast(float, x);
}

#define GLDS16(g, l) __builtin_amdgcn_global_load_lds( \
    (const __attribute__((address_space(1))) void*)(g), \
    (__attribute__((address_space(3))) void*)(l), 16, 0, 0)

// ---------------- fused f32 -> bf16 convert (4 arrays, one launch) -------------
// blocks: [0,6144) Q | [6144,10752) WUQ (scaled) | [10752,12800) KV | [12800,14848) WUKV
__global__ __launch_bounds__(256) void cvt_all(
    const float* __restrict__ Q, const float* __restrict__ WUQ,
    const float* __restrict__ KV, const float* __restrict__ WUKV,
    unsigned short* __restrict__ Qb, unsigned short* __restrict__ WUQb,
    unsigned short* __restrict__ KVb, unsigned short* __restrict__ WUKVb)
{
    int bid = blockIdx.x;
    const float* src; unsigned short* dst; float scale = 1.0f;
    if (bid < 6144)       { src = Q;    dst = Qb; }
    else if (bid < 10752) { src = WUQ;  dst = WUQb; bid -= 6144; scale = SCALE_F * LOG2E; }
    else if (bid < 12800) { src = KV;   dst = KVb;  bid -= 10752; }
    else                  { src = WUKV; dst = WUKVb; bid -= 12800; }
    int i = (bid * 256 + threadIdx.x) * 4;
    float4 v = *(const float4*)(src + i);
    ushort4 o = { f2bf(v.x * scale), f2bf(v.y * scale), f2bf(v.z * scale), f2bf(v.w * scale) };
    *(ushort4*)(dst + i) = o;
}

// ---------------- bf16 GEMM, m97 structure: 128x128 tile, BK=64 ----------------
// C[m][n] = sum_k A[m][k]*B[n][k].  SPLIT_KV: write k_nope (cols d<128 per head)
// to C[row][h*128+d] (2048 cols) and v transposed to vT[(b*16+h)*128+vd][s].
template<bool SPLIT_KV>
__global__ __launch_bounds__(256) void gemm_bf16(
    const unsigned short* __restrict__ A, const unsigned short* __restrict__ B,
    unsigned short* __restrict__ C, unsigned short* __restrict__ vT,
    int M, int N, int K)
{
    __shared__ unsigned short As[128 * 64];
    __shared__ unsigned short Bs[128 * 64];
    const int t = threadIdx.x, w = t >> 6, lane = t & 63;
    const int n16 = lane & 15, quad = lane >> 4;
    const int bm = blockIdx.y * 128, bn = blockIdx.x * 128;
    const int wm = (w >> 1) * 64, wn = (w & 1) * 64;

    f32x4 acc[4][4] = {};

    // staging: wave w, instr j covers rows w*32+j*8 .. +8 (8 rows x 128B)
    const unsigned short* gA = A + (size_t)(bm + w * 32 + (lane >> 3)) * K + (lane & 7) * 8;
    const unsigned short* gB = B + (size_t)(bn + w * 32 + (lane >> 3)) * K + (lane & 7) * 8;

    for (int k0 = 0; k0 < K; k0 += 64) {
        __syncthreads();
        for (int j = 0; j < 4; j++) {
            GLDS16(gA + (size_t)j * 8 * K + k0, &As[(w * 32 + j * 8) * 64]);
            GLDS16(gB + (size_t)j * 8 * K + k0, &Bs[(w * 32 + j * 8) * 64]);
        }
        __syncthreads();
        for (int ks = 0; ks < 2; ks++) {
            short8 af[4], bfr[4];
            for (int mt = 0; mt < 4; mt++)
                af[mt] = *(const short8*)&As[(wm + mt * 16 + n16) * 64 + ks * 32 + quad * 8];
            for (int nt = 0; nt < 4; nt++)
                bfr[nt] = *(const short8*)&Bs[(wn + nt * 16 + n16) * 64 + ks * 32 + quad * 8];
            for (int mt = 0; mt < 4; mt++)
                for (int nt = 0; nt < 4; nt++)
                    acc[mt][nt] = __builtin_amdgcn_mfma_f32_16x16x32_bf16(af[mt], bfr[nt], acc[mt][nt], 0, 0, 0);
        }
    }

    if (!SPLIT_KV) {
        for (int mt = 0; mt < 4; mt++)
            for (int nt = 0; nt < 4; nt++)
                for (int r = 0; r < 4; r++)
                    C[(size_t)(bm + wm + mt * 16 + quad * 4 + r) * N + bn + wn + nt * 16 + n16]
                        = f2bf(acc[mt][nt][r]);
    } else {
        const int colbase = bn + wn;            // multiple of 64 -> d-range uniform
        if ((colbase & 255) < 128) {
            // k_nope part
            for (int mt = 0; mt < 4; mt++)
                for (int nt = 0; nt < 4; nt++) {
                    int col = colbase + nt * 16 + n16;
                    int h = col >> 8, d = col & 255;
                    for (int r = 0; r < 4; r++)
                        C[(size_t)(bm + wm + mt * 16 + quad * 4 + r) * 2048 + h * 128 + d]
                            = f2bf(acc[mt][nt][r]);
                }
        } else {
            // v part, transposed: 4 consecutive s per lane -> ushort4
            for (int mt = 0; mt < 4; mt++)
                for (int nt = 0; nt < 4; nt++) {
                    int col = colbase + nt * 16 + n16;
                    int h = col >> 8, vd = (col & 255) - 128;
                    int row0 = bm + wm + mt * 16 + quad * 4;
                    int b = row0 >> 11, s = row0 & 2047;
                    ushort4 pk = { f2bf(acc[mt][nt][0]), f2bf(acc[mt][nt][1]),
                                   f2bf(acc[mt][nt][2]), f2bf(acc[mt][nt][3]) };
                    *(ushort4*)&vT[((size_t)(b * 16 + h) * 128 + vd) * 2048 + s] = pk;
                }
        }
    }
}

// ---------------- RoPE on q_pe (in-place, bf16 qbuf) ----------------
__global__ __launch_bounds__(256) void rope_q_kernel(unsigned short* __restrict__ q,
    const float* __restrict__ cs, const float* __restrict__ sn)
{
    int idx = blockIdx.x * 256 + threadIdx.x;
    int i = idx & 31;
    int h = (idx >> 5) & 15;
    int row = idx >> 9;
    size_t base = (size_t)row * (HH * QD) + h * QD + NOPE_D;
    float x1 = bf2f(q[base + i]);
    float x2 = bf2f(q[base + 32 + i]);
    float c1 = cs[row * 64 + i],      s1 = sn[row * 64 + i];
    float c2 = cs[row * 64 + 32 + i], s2 = sn[row * 64 + 32 + i];
    q[base + i]      = f2bf(x1 * c1 - x2 * s1);
    q[base + 32 + i] = f2bf(x2 * c2 + x1 * s2);
}

// ---------------- k_pe = rope(PE), f32 -> bf16 ----------------
__global__ __launch_bounds__(256) void rope_k_kernel(const float* __restrict__ pe,
    const float* __restrict__ cs, const float* __restrict__ sn,
    unsigned short* __restrict__ kpe)
{
    int idx = blockIdx.x * 256 + threadIdx.x;
    int i = idx & 31;
    int row = idx >> 5;
    float x1 = pe[row * 64 + i], x2 = pe[row * 64 + 32 + i];
    float c1 = cs[row * 64 + i],      s1 = sn[row * 64 + i];
    float c2 = cs[row * 64 + 32 + i], s2 = sn[row * 64 + 32 + i];
    kpe[row * 64 + i]      = f2bf(x1 * c1 - x2 * s1);
    kpe[row * 64 + 32 + i] = f2bf(x2 * c2 + x1 * s2);
}

// ---------------- flash attention, causal, balanced pairs ----------------
// grid (16,16,2): block p handles q-tiles {31-p, p} -> uniform 33 k-iters.
// scores arrive pre-scaled by SCALE*log2e (folded into WUQ) -> softmax base 2.
__global__ __launch_bounds__(256) void attn_kernel(
    const unsigned short* __restrict__ qbuf,   // (4096, 3072)
    const unsigned short* __restrict__ knope,  // (4096, 2048): [row][h*128+d]
    const unsigned short* __restrict__ kpe,    // (4096, 64)
    const unsigned short* __restrict__ vT,     // [(b*16+h)*128+vd][2048]
    float* __restrict__ out)                   // (B,S,H,128) f32
{
    const int p = blockIdx.x;
    const int h = blockIdx.y, b = blockIdx.z;
    const int t = threadIdx.x, w = t >> 6, lane = t & 63;
    const int n16 = lane & 15, quad = lane >> 4;

    __shared__ unsigned short Kn[64 * 128];
    __shared__ unsigned short Kp[64 * 64];
    __shared__ unsigned short Vt[128 * 64];
    __shared__ unsigned short Ps[4][16 * 72];

    const unsigned short* knb = knope + (size_t)b * 2048 * 2048 + h * 128;
    const unsigned short* kpb = kpe + (size_t)b * 2048 * 64;
    const unsigned short* vtb = vT + (size_t)(b * 16 + h) * 128 * 2048;

    for (int phase = 0; phase < 2; phase++) {
        const int qt = phase ? p : 31 - p;

        short8 qf[6];
        {
            size_t grow = (size_t)(b * SS + qt * 64 + w * 16 + n16);
            const unsigned short* qp = qbuf + grow * (HH * QD) + h * QD + quad * 8;
            for (int ks = 0; ks < 6; ks++) qf[ks] = *(const short8*)(qp + ks * 32);
        }

        f32x4 O[8] = {};
        float m_i[4], l_i[4];
        for (int r = 0; r < 4; r++) { m_i[r] = -INFINITY; l_i[r] = 0.f; }

        for (int kt = 0; kt <= qt; kt++) {
            __syncthreads();
            {   // K nope tile: 64 keys x 128, 4 instrs/wave (4 rows each)
                const unsigned short* g = knb + (size_t)(kt * 64 + w * 16 + (lane >> 4)) * 2048 + (lane & 15) * 8;
                for (int j = 0; j < 4; j++)
                    GLDS16(g + (size_t)j * 4 * 2048, &Kn[(w * 16 + j * 4) * 128]);
            }
            {   // K pe tile: 64 keys x 64, 2 instrs/wave (8 rows each)
                const unsigned short* g = kpb + (size_t)(kt * 64 + w * 16 + (lane >> 3)) * 64 + (lane & 7) * 8;
                for (int j = 0; j < 2; j++)
                    GLDS16(g + (size_t)j * 8 * 64, &Kp[(w * 16 + j * 8) * 64]);
            }
            {   // V^T tile: 128 vd x 64 keys, 4 instrs/wave (8 rows each)
                const unsigned short* g = vtb + (size_t)(w * 32 + (lane >> 3)) * 2048 + kt * 64 + (lane & 7) * 8;
                for (int j = 0; j < 4; j++)
                    GLDS16(g + (size_t)j * 8 * 2048, &Vt[(w * 32 + j * 8) * 64]);
            }
            __syncthreads();

            // QK^T (pre-scaled)
            f32x4 Sg[4];
            for (int nt = 0; nt < 4; nt++) {
                f32x4 a = {};
                for (int ks = 0; ks < 4; ks++) {
                    short8 bfr = *(const short8*)&Kn[(nt * 16 + n16) * 128 + ks * 32 + quad * 8];
                    a = __builtin_amdgcn_mfma_f32_16x16x32_bf16(qf[ks], bfr, a, 0, 0, 0);
                }
                for (int ks = 0; ks < 2; ks++) {
                    short8 bfr = *(const short8*)&Kp[(nt * 16 + n16) * 64 + ks * 32 + quad * 8];
                    a = __builtin_amdgcn_mfma_f32_16x16x32_bf16(qf[4 + ks], bfr, a, 0, 0, 0);
                }
                Sg[nt] = a;
            }
            if (kt == qt) {
                for (int nt = 0; nt < 4; nt++)
                    for (int r = 0; r < 4; r++) {
                        int col = nt * 16 + n16, row = w * 16 + quad * 4 + r;
                        if (col > row) Sg[nt][r] = -INFINITY;
                    }
            }
            // online softmax, base 2
            float alpha[4];
            for (int r = 0; r < 4; r++) {
                float mx = fmaxf(fmaxf(Sg[0][r], Sg[1][r]), fmaxf(Sg[2][r], Sg[3][r]));
                for (int off = 1; off < 16; off <<= 1) mx = fmaxf(mx, __shfl_xor(mx, off, 64));
                float mnew = fmaxf(m_i[r], mx);
                alpha[r] = exp2f(m_i[r] - mnew);
                m_i[r] = mnew;
                float rs = 0.f;
                for (int nt = 0; nt < 4; nt++) {
                    float pv = exp2f(Sg[nt][r] - mnew);
                    Sg[nt][r] = pv;
                    rs += pv;
                }
                for (int off = 1; off < 16; off <<= 1) rs += __shfl_xor(rs, off, 64);
                l_i[r] = l_i[r] * alpha[r] + rs;
            }
            // P -> per-wave LDS (wave-internal RAW; compiler inserts waits)
            for (int nt = 0; nt < 4; nt++)
                for (int r = 0; r < 4; r++)
                    Ps[w][(quad * 4 + r) * 72 + nt * 16 + n16] = f2bf(Sg[nt][r]);
            for (int v8 = 0; v8 < 8; v8++)
                for (int r = 0; r < 4; r++) O[v8][r] *= alpha[r];
            // PV
            for (int ks = 0; ks < 2; ks++) {
                short8 pa = *(const short8*)&Ps[w][n16 * 72 + ks * 32 + quad * 8];
                for (int v8 = 0; v8 < 8; v8++) {
                    short8 vb = *(const short8*)&Vt[(v8 * 16 + n16) * 64 + ks * 32 + quad * 8];
                    O[v8] = __builtin_amdgcn_mfma_f32_16x16x32_bf16(pa, vb, O[v8], 0, 0, 0);
                }
            }
        }

        for (int r = 0; r < 4; r++) {
            float inv = 1.f / l_i[r];
            size_t qrow = (size_t)(b * SS + qt * 64 + w * 16 + quad * 4 + r);
            float* op = out + (qrow * HH + h) * VDIM;
            for (int v8 = 0; v8 < 8; v8++)
                op[v8 * 16 + n16] = O[v8][r] * inv;
        }
    }
}

extern "C" void kernel_launch(void* const* d_in, const int* in_sizes, int n_in,
                              void* d_out, int out_size, void* d_ws, size_t ws_size,
                              hipStream_t stream) {
    const float* Q    = (const float*)d_in[0];
    const float* KV   = (const float*)d_in[1];
    const float* PE   = (const float*)d_in[2];
    const float* WUQ  = (const float*)d_in[3];
    const float* WUKV = (const float*)d_in[4];
    const float* cosp = (const float*)d_in[5];
    const float* sinp = (const float*)d_in[6];
    float* out = (float*)d_out;

    unsigned short* qbuf  = (unsigned short*)d_ws;                 // 4096x3072
    unsigned short* knope = qbuf  + (size_t)4096 * 3072;           // 4096x2048
    unsigned short* vT    = knope + (size_t)4096 * 2048;           // 4096x2048 (transposed v)
    unsigned short* kpe   = vT    + (size_t)4096 * 2048;           // 4096x64
    unsigned short* Qb    = kpe   + (size_t)4096 * 64;             // 4096x1536
    unsigned short* WUQb  = Qb    + (size_t)4096 * 1536;           // 3072x1536
    unsigned short* KVb   = WUQb  + (size_t)3072 * 1536;           // 4096x512
    unsigned short* WUKVb = KVb   + (size_t)4096 * 512;            // 4096x512

    cvt_all<<<14848, 256, 0, stream>>>(Q, WUQ, KV, WUKV, Qb, WUQb, KVb, WUKVb);
    // q = Q @ WUQ^T (pre-scaled): M=4096, N=3072, K=1536
    gemm_bf16<false><<<dim3(24, 32), 256, 0, stream>>>(Qb, WUQb, qbuf, nullptr, 4096, 3072, 1536);
    // kv = KV @ WUKV^T, split epilogue: M=4096, N=4096, K=512
    gemm_bf16<true><<<dim3(32, 32), 256, 0, stream>>>(KVb, WUKVb, knope, vT, 4096, 4096, 512);
    rope_q_kernel<<<(4096 * 16 * 32) / 256, 256, 0, stream>>>(qbuf, cosp, sinp);
    rope_k_kernel<<<(4096 * 32) / 256, 256, 0, stream>>>(PE, cosp, sinp, kpe);
    attn_kernel<<<dim3(16, HH, 2), 256, 0, stream>>>(qbuf, knope, kpe, vT, out);
}

// Round 3
// 387.277 us; speedup vs baseline: 1.4202x; 1.0415x over previous
//
#include <hip/hip_runtime.h>

typedef __attribute__((ext_vector_type(8))) short short8;
typedef __attribute__((ext_vector_type(4))) float f32x4;

#define SS 2048
#define HH 16
#define NOPE_D 128
#define ROPE_D 64
#define VDIM 128
#define QD 192
#define SCALE_F 0.07216878364870323f       // 1/sqrt(192)
#define LOG2E 1.4426950408889634f

__device__ __forceinline__ unsigned short f2bf(float f) {
    unsigned int x = __builtin_bit_cast(unsigned int, f);
    unsigned int r = (x + 0x7fffu + ((x >> 16) & 1u)) >> 16;
    return (unsigned short)r;
}
__device__ __forceinline__ float bf2f(unsigned short u) {
    unsigned int x = ((unsigned int)u) << 16;
    return __builtin_bit_cast(float, x);
}

#define GLDS16(g, l) __builtin_amdgcn_global_load_lds( \
    (const __attribute__((address_space(1))) void*)(g), \
    (__attribute__((address_space(3))) void*)(l), 16, 0, 0)

// ---------------- fused f32 -> bf16 convert (4 arrays, one launch) -------------
__global__ __launch_bounds__(256) void cvt_all(
    const float* __restrict__ Q, const float* __restrict__ WUQ,
    const float* __restrict__ KV, const float* __restrict__ WUKV,
    unsigned short* __restrict__ Qb, unsigned short* __restrict__ WUQb,
    unsigned short* __restrict__ KVb, unsigned short* __restrict__ WUKVb)
{
    int bid = blockIdx.x;
    const float* src; unsigned short* dst; float scale = 1.0f;
    if (bid < 6144)       { src = Q;    dst = Qb; }
    else if (bid < 10752) { src = WUQ;  dst = WUQb; bid -= 6144; scale = SCALE_F * LOG2E; }
    else if (bid < 12800) { src = KV;   dst = KVb;  bid -= 10752; }
    else                  { src = WUKV; dst = WUKVb; bid -= 12800; }
    int i = (bid * 256 + threadIdx.x) * 4;
    float4 v = *(const float4*)(src + i);
    ushort4 o = { f2bf(v.x * scale), f2bf(v.y * scale), f2bf(v.z * scale), f2bf(v.w * scale) };
    *(ushort4*)(dst + i) = o;
}

// ---------------- bf16 GEMM, m97 structure: 128x128 tile, BK=64 ----------------
template<bool SPLIT_KV>
__global__ __launch_bounds__(256) void gemm_bf16(
    const unsigned short* __restrict__ A, const unsigned short* __restrict__ B,
    unsigned short* __restrict__ C, unsigned short* __restrict__ vT,
    int M, int N, int K)
{
    __shared__ unsigned short As[128 * 64];
    __shared__ unsigned short Bs[128 * 64];
    const int t = threadIdx.x, w = t >> 6, lane = t & 63;
    const int n16 = lane & 15, quad = lane >> 4;
    const int bm = blockIdx.y * 128, bn = blockIdx.x * 128;
    const int wm = (w >> 1) * 64, wn = (w & 1) * 64;

    f32x4 acc[4][4] = {};

    const unsigned short* gA = A + (size_t)(bm + w * 32 + (lane >> 3)) * K + (lane & 7) * 8;
    const unsigned short* gB = B + (size_t)(bn + w * 32 + (lane >> 3)) * K + (lane & 7) * 8;

    for (int k0 = 0; k0 < K; k0 += 64) {
        __syncthreads();
        for (int j = 0; j < 4; j++) {
            GLDS16(gA + (size_t)j * 8 * K + k0, &As[(w * 32 + j * 8) * 64]);
            GLDS16(gB + (size_t)j * 8 * K + k0, &Bs[(w * 32 + j * 8) * 64]);
        }
        __syncthreads();
        for (int ks = 0; ks < 2; ks++) {
            short8 af[4], bfr[4];
            for (int mt = 0; mt < 4; mt++)
                af[mt] = *(const short8*)&As[(wm + mt * 16 + n16) * 64 + ks * 32 + quad * 8];
            for (int nt = 0; nt < 4; nt++)
                bfr[nt] = *(const short8*)&Bs[(wn + nt * 16 + n16) * 64 + ks * 32 + quad * 8];
            for (int mt = 0; mt < 4; mt++)
                for (int nt = 0; nt < 4; nt++)
                    acc[mt][nt] = __builtin_amdgcn_mfma_f32_16x16x32_bf16(af[mt], bfr[nt], acc[mt][nt], 0, 0, 0);
        }
    }

    if (!SPLIT_KV) {
        for (int mt = 0; mt < 4; mt++)
            for (int nt = 0; nt < 4; nt++)
                for (int r = 0; r < 4; r++)
                    C[(size_t)(bm + wm + mt * 16 + quad * 4 + r) * N + bn + wn + nt * 16 + n16]
                        = f2bf(acc[mt][nt][r]);
    } else {
        const int colbase = bn + wn;
        if ((colbase & 255) < 128) {
            for (int mt = 0; mt < 4; mt++)
                for (int nt = 0; nt < 4; nt++) {
                    int col = colbase + nt * 16 + n16;
                    int h = col >> 8, d = col & 255;
                    for (int r = 0; r < 4; r++)
                        C[(size_t)(bm + wm + mt * 16 + quad * 4 + r) * 2048 + h * 128 + d]
                            = f2bf(acc[mt][nt][r]);
                }
        } else {
            for (int mt = 0; mt < 4; mt++)
                for (int nt = 0; nt < 4; nt++) {
                    int col = colbase + nt * 16 + n16;
                    int h = col >> 8, vd = (col & 255) - 128;
                    int row0 = bm + wm + mt * 16 + quad * 4;
                    int b = row0 >> 11, s = row0 & 2047;
                    ushort4 pk = { f2bf(acc[mt][nt][0]), f2bf(acc[mt][nt][1]),
                                   f2bf(acc[mt][nt][2]), f2bf(acc[mt][nt][3]) };
                    *(ushort4*)&vT[((size_t)(b * 16 + h) * 128 + vd) * 2048 + s] = pk;
                }
        }
    }
}

// ---------------- RoPE on q_pe (in-place, bf16 qbuf) ----------------
__global__ __launch_bounds__(256) void rope_q_kernel(unsigned short* __restrict__ q,
    const float* __restrict__ cs, const float* __restrict__ sn)
{
    int idx = blockIdx.x * 256 + threadIdx.x;
    int i = idx & 31;
    int h = (idx >> 5) & 15;
    int row = idx >> 9;
    size_t base = (size_t)row * (HH * QD) + h * QD + NOPE_D;
    float x1 = bf2f(q[base + i]);
    float x2 = bf2f(q[base + 32 + i]);
    float c1 = cs[row * 64 + i],      s1 = sn[row * 64 + i];
    float c2 = cs[row * 64 + 32 + i], s2 = sn[row * 64 + 32 + i];
    q[base + i]      = f2bf(x1 * c1 - x2 * s1);
    q[base + 32 + i] = f2bf(x2 * c2 + x1 * s2);
}

// ---------------- k_pe = rope(PE), f32 -> bf16 ----------------
__global__ __launch_bounds__(256) void rope_k_kernel(const float* __restrict__ pe,
    const float* __restrict__ cs, const float* __restrict__ sn,
    unsigned short* __restrict__ kpe)
{
    int idx = blockIdx.x * 256 + threadIdx.x;
    int i = idx & 31;
    int row = idx >> 5;
    float x1 = pe[row * 64 + i], x2 = pe[row * 64 + 32 + i];
    float c1 = cs[row * 64 + i],      s1 = sn[row * 64 + i];
    float c2 = cs[row * 64 + 32 + i], s2 = sn[row * 64 + 32 + i];
    kpe[row * 64 + i]      = f2bf(x1 * c1 - x2 * s1);
    kpe[row * 64 + 32 + i] = f2bf(x2 * c2 + x1 * s2);
}

// ---------------- flash attention, causal, BQ=128, paired tiles ----------------
// grid (8,16,2): block p handles q-tiles(128 rows) {15-p, p} -> uniform 34 k-iters.
// 4 waves x 32 q-rows (2 m-frags). XOR-swizzled LDS (slot = chunk ^ (row&7)).
// scores pre-scaled by SCALE*log2e (folded into WUQ) -> softmax base 2.
__global__ __launch_bounds__(256, 1) void attn_kernel(
    const unsigned short* __restrict__ qbuf,   // (4096, 3072)
    const unsigned short* __restrict__ knope,  // (4096, 2048): [row][h*128+d]
    const unsigned short* __restrict__ kpe,    // (4096, 64)
    const unsigned short* __restrict__ vT,     // [(b*16+h)*128+vd][2048]
    float* __restrict__ out)                   // (B,S,H,128) f32
{
    const int p = blockIdx.x;
    const int h = blockIdx.y, b = blockIdx.z;
    const int t = threadIdx.x, w = t >> 6, lane = t & 63;
    const int n16 = lane & 15, quad = lane >> 4;

    __shared__ unsigned short Kn[64 * 128];    // [key][slot^..], 16 KB
    __shared__ unsigned short Kp[64 * 64];     // 8 KB
    __shared__ unsigned short Vt[128 * 64];    // [vd][slot^..], 16 KB
    __shared__ unsigned short Ps[4][32 * 72];  // per-wave P 32x64 (+pad), 18 KB

    const unsigned short* knb = knope + (size_t)b * 2048 * 2048 + h * 128;
    const unsigned short* kpb = kpe + (size_t)b * 2048 * 64;
    const unsigned short* vtb = vT + (size_t)(b * 16 + h) * 128 * 2048;

    for (int phase = 0; phase < 2; phase++) {
        const int qt = phase ? p : 15 - p;

        // Q fragments: wave w owns rows qt*128 + w*32 + mt*16 + n16
        short8 qf[2][6];
        for (int mt = 0; mt < 2; mt++) {
            size_t grow = (size_t)(b * SS + qt * 128 + w * 32 + mt * 16 + n16);
            const unsigned short* qp = qbuf + grow * (HH * QD) + h * QD + quad * 8;
            for (int ks = 0; ks < 6; ks++) qf[mt][ks] = *(const short8*)(qp + ks * 32);
        }

        f32x4 O[2][8] = {};
        float m_i[2][4], ps[2][4];
        for (int mt = 0; mt < 2; mt++)
            for (int r = 0; r < 4; r++) { m_i[mt][r] = -INFINITY; ps[mt][r] = 0.f; }

        const int nkt = 2 * qt + 2;
        for (int kt = 0; kt < nkt; kt++) {
            __syncthreads();
            {   // K nope: 64 keys x 128 shorts; wave w rows w*16.., 4 glds x 4 rows
                int r = w * 16 + (lane >> 4);           // + j*4
                int sl = lane & 15;
                for (int j = 0; j < 4; j++) {
                    int rr = r + j * 4;
                    const unsigned short* g = knb + (size_t)(kt * 64 + rr) * 2048 + ((sl ^ (rr & 7)) * 8);
                    GLDS16(g, &Kn[(w * 16 + j * 4) * 128]);
                }
            }
            {   // K pe: 64 keys x 64 shorts; 2 glds x 8 rows
                int r = w * 16 + (lane >> 3);
                int sl = lane & 7;
                for (int j = 0; j < 2; j++) {
                    int rr = r + j * 8;
                    const unsigned short* g = kpb + (size_t)(kt * 64 + rr) * 64 + ((sl ^ (rr & 7)) * 8);
                    GLDS16(g, &Kp[(w * 16 + j * 8) * 64]);
                }
            }
            {   // V^T: 128 vd x 64 keys; 4 glds x 8 rows
                int r = w * 32 + (lane >> 3);
                int sl = lane & 7;
                for (int j = 0; j < 4; j++) {
                    int rr = r + j * 8;
                    const unsigned short* g = vtb + (size_t)rr * 2048 + kt * 64 + ((sl ^ (rr & 7)) * 8);
                    GLDS16(g, &Vt[(w * 32 + j * 8) * 64]);
                }
            }
            __syncthreads();

            const bool edge = (kt >= 2 * qt);   // last two k-tiles need masking

            for (int mt = 0; mt < 2; mt++) {
                // QK^T for this m-frag: B-frags re-read (registers can't hold all)
                f32x4 Sg[4];
                for (int nt = 0; nt < 4; nt++) {
                    int key = nt * 16 + n16;
                    int kx = key & 7;
                    f32x4 a = {};
                    for (int ks = 0; ks < 4; ks++) {
                        short8 bfr = *(const short8*)&Kn[key * 128 + (((ks * 4 + quad) ^ kx) * 8)];
                        a = __builtin_amdgcn_mfma_f32_16x16x32_bf16(qf[mt][ks], bfr, a, 0, 0, 0);
                    }
                    for (int ks = 0; ks < 2; ks++) {
                        short8 bfr = *(const short8*)&Kp[key * 64 + (((ks * 4 + quad) ^ kx) * 8)];
                        a = __builtin_amdgcn_mfma_f32_16x16x32_bf16(qf[mt][4 + ks], bfr, a, 0, 0, 0);
                    }
                    Sg[nt] = a;
                }
                if (edge) {
                    int rowg = qt * 128 + w * 32 + mt * 16 + quad * 4;
                    for (int nt = 0; nt < 4; nt++) {
                        int colg = kt * 64 + nt * 16 + n16;
                        for (int r = 0; r < 4; r++)
                            if (colg > rowg + r) Sg[nt][r] = -INFINITY;
                    }
                }
                // online softmax (base 2), deferred l-reduction
                for (int r = 0; r < 4; r++) {
                    float mx = fmaxf(fmaxf(Sg[0][r], Sg[1][r]), fmaxf(Sg[2][r], Sg[3][r]));
                    for (int off = 1; off < 16; off <<= 1) mx = fmaxf(mx, __shfl_xor(mx, off, 64));
                    float mnew = fmaxf(m_i[mt][r], mx);
                    float alpha = exp2f(m_i[mt][r] - mnew);
                    m_i[mt][r] = mnew;
                    float rs = 0.f;
                    for (int nt = 0; nt < 4; nt++) {
                        float pv = exp2f(Sg[nt][r] - mnew);
                        Sg[nt][r] = pv;
                        rs += pv;
                    }
                    ps[mt][r] = ps[mt][r] * alpha + rs;
                    for (int v8 = 0; v8 < 8; v8++) O[mt][v8][r] *= alpha;
                }
                // P -> per-wave LDS rows mt*16..+15 (wave-internal RAW)
                for (int nt = 0; nt < 4; nt++)
                    for (int r = 0; r < 4; r++)
                        Ps[w][(mt * 16 + quad * 4 + r) * 72 + nt * 16 + n16] = f2bf(Sg[nt][r]);
            }
            // PV for both m-frags, V-frags shared
            for (int ks = 0; ks < 2; ks++) {
                short8 pa0 = *(const short8*)&Ps[w][(0 + n16) * 72 + ks * 32 + quad * 8];
                short8 pa1 = *(const short8*)&Ps[w][(16 + n16) * 72 + ks * 32 + quad * 8];
                for (int v8 = 0; v8 < 8; v8++) {
                    int vd = v8 * 16 + n16;
                    short8 vb = *(const short8*)&Vt[vd * 64 + (((ks * 4 + quad) ^ (vd & 7)) * 8)];
                    O[0][v8] = __builtin_amdgcn_mfma_f32_16x16x32_bf16(pa0, vb, O[0][v8], 0, 0, 0);
                    O[1][v8] = __builtin_amdgcn_mfma_f32_16x16x32_bf16(pa1, vb, O[1][v8], 0, 0, 0);
                }
            }
        }

        // epilogue: reduce l across the 16-lane row group, write out
        for (int mt = 0; mt < 2; mt++)
            for (int r = 0; r < 4; r++) {
                float l = ps[mt][r];
                for (int off = 1; off < 16; off <<= 1) l += __shfl_xor(l, off, 64);
                float inv = 1.f / l;
                size_t qrow = (size_t)(b * SS + qt * 128 + w * 32 + mt * 16 + quad * 4 + r);
                float* op = out + (qrow * HH + h) * VDIM;
                for (int v8 = 0; v8 < 8; v8++)
                    op[v8 * 16 + n16] = O[mt][v8][r] * inv;
            }
    }
}

extern "C" void kernel_launch(void* const* d_in, const int* in_sizes, int n_in,
                              void* d_out, int out_size, void* d_ws, size_t ws_size,
                              hipStream_t stream) {
    const float* Q    = (const float*)d_in[0];
    const float* KV   = (const float*)d_in[1];
    const float* PE   = (const float*)d_in[2];
    const float* WUQ  = (const float*)d_in[3];
    const float* WUKV = (const float*)d_in[4];
    const float* cosp = (const float*)d_in[5];
    const float* sinp = (const float*)d_in[6];
    float* out = (float*)d_out;

    unsigned short* qbuf  = (unsigned short*)d_ws;                 // 4096x3072
    unsigned short* knope = qbuf  + (size_t)4096 * 3072;           // 4096x2048
    unsigned short* vT    = knope + (size_t)4096 * 2048;           // 4096x2048
    unsigned short* kpe   = vT    + (size_t)4096 * 2048;           // 4096x64
    unsigned short* Qb    = kpe   + (size_t)4096 * 64;             // 4096x1536
    unsigned short* WUQb  = Qb    + (size_t)4096 * 1536;           // 3072x1536
    unsigned short* KVb   = WUQb  + (size_t)3072 * 1536;           // 4096x512
    unsigned short* WUKVb = KVb   + (size_t)4096 * 512;            // 4096x512

    cvt_all<<<14848, 256, 0, stream>>>(Q, WUQ, KV, WUKV, Qb, WUQb, KVb, WUKVb);
    gemm_bf16<false><<<dim3(24, 32), 256, 0, stream>>>(Qb, WUQb, qbuf, nullptr, 4096, 3072, 1536);
    gemm_bf16<true><<<dim3(32, 32), 256, 0, stream>>>(KVb, WUKVb, knope, vT, 4096, 4096, 512);
    rope_q_kernel<<<(4096 * 16 * 32) / 256, 256, 0, stream>>>(qbuf, cosp, sinp);
    rope_k_kernel<<<(4096 * 32) / 256, 256, 0, stream>>>(PE, cosp, sinp, kpe);
    attn_kernel<<<dim3(8, HH, 2), 256, 0, stream>>>(qbuf, knope, kpe, vT, out);
}

// Round 4
// 338.823 us; speedup vs baseline: 1.6233x; 1.1430x over previous
//
#include <hip/hip_runtime.h>

typedef __attribute__((ext_vector_type(8))) short short8;
typedef __attribute__((ext_vector_type(4))) float f32x4;

#define SS 2048
#define HH 16
#define NOPE_D 128
#define ROPE_D 64
#define VDIM 128
#define QD 192
#define SCALE_F 0.07216878364870323f       // 1/sqrt(192)
#define LOG2E 1.4426950408889634f

__device__ __forceinline__ unsigned short f2bf(float f) {
    unsigned int x = __builtin_bit_cast(unsigned int, f);
    unsigned int r = (x + 0x7fffu + ((x >> 16) & 1u)) >> 16;
    return (unsigned short)r;
}

#define GLDS16(g, l) __builtin_amdgcn_global_load_lds( \
    (const __attribute__((address_space(1))) void*)(g), \
    (__attribute__((address_space(3))) void*)(l), 16, 0, 0)

// DPP cross-lane (VALU pipe, not DS): 16-lane butterfly reduce
#define DPPF(x, ctrl) __builtin_bit_cast(float, __builtin_amdgcn_update_dpp( \
    0, __builtin_bit_cast(int, (float)(x)), (ctrl), 0xf, 0xf, true))
__device__ __forceinline__ float rowmax16(float x) {
    x = fmaxf(x, DPPF(x, 0xB1));   // quad_perm [1,0,3,2]
    x = fmaxf(x, DPPF(x, 0x4E));   // quad_perm [2,3,0,1]
    x = fmaxf(x, DPPF(x, 0x141));  // row_half_mirror
    x = fmaxf(x, DPPF(x, 0x140));  // row_mirror
    return x;
}
__device__ __forceinline__ float rowsum16(float x) {
    x += DPPF(x, 0xB1);
    x += DPPF(x, 0x4E);
    x += DPPF(x, 0x141);
    x += DPPF(x, 0x140);
    return x;
}

// ------- fused f32->bf16 convert (4 arrays) + rope_k, one launch -------
// blocks: [0,6144) Q | [6144,10752) WUQ(scaled) | [10752,12800) KV |
//         [12800,14848) WUKV | [14848,15360) rope_k
__global__ __launch_bounds__(256) void cvt_all(
    const float* __restrict__ Q, const float* __restrict__ WUQ,
    const float* __restrict__ KV, const float* __restrict__ WUKV,
    const float* __restrict__ PE, const float* __restrict__ cs, const float* __restrict__ sn,
    unsigned short* __restrict__ Qb, unsigned short* __restrict__ WUQb,
    unsigned short* __restrict__ KVb, unsigned short* __restrict__ WUKVb,
    unsigned short* __restrict__ kpe)
{
    int bid = blockIdx.x;
    if (bid >= 14848) {   // rope_k: PE (4096x64) -> kpe bf16
        int idx = (bid - 14848) * 256 + threadIdx.x;   // [0, 131072)
        int i = idx & 31, row = idx >> 5;
        float x1 = PE[row * 64 + i], x2 = PE[row * 64 + 32 + i];
        float c1 = cs[row * 64 + i],      s1 = sn[row * 64 + i];
        float c2 = cs[row * 64 + 32 + i], s2 = sn[row * 64 + 32 + i];
        kpe[row * 64 + i]      = f2bf(x1 * c1 - x2 * s1);
        kpe[row * 64 + 32 + i] = f2bf(x2 * c2 + x1 * s2);
        return;
    }
    const float* src; unsigned short* dst; float scale = 1.0f;
    if (bid < 6144)       { src = Q;    dst = Qb; }
    else if (bid < 10752) { src = WUQ;  dst = WUQb; bid -= 6144; scale = SCALE_F * LOG2E; }
    else if (bid < 12800) { src = KV;   dst = KVb;  bid -= 10752; }
    else                  { src = WUKV; dst = WUKVb; bid -= 12800; }
    int i = (bid * 256 + threadIdx.x) * 4;
    float4 v = *(const float4*)(src + i);
    ushort4 o = { f2bf(v.x * scale), f2bf(v.y * scale), f2bf(v.z * scale), f2bf(v.w * scale) };
    *(ushort4*)(dst + i) = o;
}

// ------- bf16 GEMM, 128x128 tile, BK=64. ROPE: apply rope to pe col-groups
//         in-register (gemm1). SPLIT_KV: knope + transposed-v epilogue (gemm2).
template<bool SPLIT_KV, bool ROPE>
__global__ __launch_bounds__(256) void gemm_bf16(
    const unsigned short* __restrict__ A, const unsigned short* __restrict__ B,
    unsigned short* __restrict__ C, unsigned short* __restrict__ vT,
    const float* __restrict__ cs, const float* __restrict__ sn,
    int M, int N, int K)
{
    __shared__ unsigned short As[128 * 64];
    __shared__ unsigned short Bs[128 * 64];
    const int t = threadIdx.x, w = t >> 6, lane = t & 63;
    const int n16 = lane & 15, quad = lane >> 4;
    const int bm = blockIdx.y * 128, bn = blockIdx.x * 128;
    const int wm = (w >> 1) * 64, wn = (w & 1) * 64;

    f32x4 acc[4][4] = {};

    const unsigned short* gA = A + (size_t)(bm + w * 32 + (lane >> 3)) * K + (lane & 7) * 8;
    const unsigned short* gB = B + (size_t)(bn + w * 32 + (lane >> 3)) * K + (lane & 7) * 8;

    for (int k0 = 0; k0 < K; k0 += 64) {
        __syncthreads();
        for (int j = 0; j < 4; j++) {
            GLDS16(gA + (size_t)j * 8 * K + k0, &As[(w * 32 + j * 8) * 64]);
            GLDS16(gB + (size_t)j * 8 * K + k0, &Bs[(w * 32 + j * 8) * 64]);
        }
        __syncthreads();
        for (int ks = 0; ks < 2; ks++) {
            short8 af[4], bfr[4];
            for (int mt = 0; mt < 4; mt++)
                af[mt] = *(const short8*)&As[(wm + mt * 16 + n16) * 64 + ks * 32 + quad * 8];
            for (int nt = 0; nt < 4; nt++)
                bfr[nt] = *(const short8*)&Bs[(wn + nt * 16 + n16) * 64 + ks * 32 + quad * 8];
            for (int mt = 0; mt < 4; mt++)
                for (int nt = 0; nt < 4; nt++)
                    acc[mt][nt] = __builtin_amdgcn_mfma_f32_16x16x32_bf16(af[mt], bfr[nt], acc[mt][nt], 0, 0, 0);
        }
    }

    if (!SPLIT_KV) {
        const int colbase = bn + wn;
        const bool is_pe = ROPE && ((colbase % 192) >= 128);   // pe groups 64-aligned
        if (is_pe) {
            for (int mt = 0; mt < 4; mt++)
                for (int r = 0; r < 4; r++) {
                    int row = bm + wm + mt * 16 + quad * 4 + r;
                    const float* cr = cs + row * 64;
                    const float* sr = sn + row * 64;
                    for (int nt = 0; nt < 2; nt++) {
                        int i = nt * 16 + n16;
                        float x1 = acc[mt][nt][r], x2 = acc[mt][nt + 2][r];
                        float o1 = x1 * cr[i] - x2 * sr[i];
                        float o2 = x2 * cr[32 + i] + x1 * sr[32 + i];
                        C[(size_t)row * N + colbase + i] = f2bf(o1);
                        C[(size_t)row * N + colbase + 32 + i] = f2bf(o2);
                    }
                }
        } else {
            for (int mt = 0; mt < 4; mt++)
                for (int nt = 0; nt < 4; nt++)
                    for (int r = 0; r < 4; r++)
                        C[(size_t)(bm + wm + mt * 16 + quad * 4 + r) * N + colbase + nt * 16 + n16]
                            = f2bf(acc[mt][nt][r]);
        }
    } else {
        const int colbase = bn + wn;
        if ((colbase & 255) < 128) {
            for (int mt = 0; mt < 4; mt++)
                for (int nt = 0; nt < 4; nt++) {
                    int col = colbase + nt * 16 + n16;
                    int h = col >> 8, d = col & 255;
                    for (int r = 0; r < 4; r++)
                        C[(size_t)(bm + wm + mt * 16 + quad * 4 + r) * 2048 + h * 128 + d]
                            = f2bf(acc[mt][nt][r]);
                }
        } else {
            for (int mt = 0; mt < 4; mt++)
                for (int nt = 0; nt < 4; nt++) {
                    int col = colbase + nt * 16 + n16;
                    int h = col >> 8, vd = (col & 255) - 128;
                    int row0 = bm + wm + mt * 16 + quad * 4;
                    int b = row0 >> 11, s = row0 & 2047;
                    ushort4 pk = { f2bf(acc[mt][nt][0]), f2bf(acc[mt][nt][1]),
                                   f2bf(acc[mt][nt][2]), f2bf(acc[mt][nt][3]) };
                    *(ushort4*)&vT[((size_t)(b * 16 + h) * 128 + vd) * 2048 + s] = pk;
                }
        }
    }
}

// ------- flash attention, causal, BQ=128, 512 balanced blocks, 2 blocks/CU ----
// bid<256: qt=15-(bid>>5); else qt=(bid-256)>>5  -> CU_i gets 17 iter-slots.
// XOR-swizzled LDS (slot = chunk ^ (row&7)); softmax base 2 (scale folded in WUQ);
// DPP (VALU) reductions instead of ds_swizzle shuffles.
__global__ __launch_bounds__(256, 2) void attn_kernel(
    const unsigned short* __restrict__ qbuf,   // (4096, 3072) roped
    const unsigned short* __restrict__ knope,  // (4096, 2048): [row][h*128+d]
    const unsigned short* __restrict__ kpe,    // (4096, 64) roped
    const unsigned short* __restrict__ vT,     // [(b*16+h)*128+vd][2048]
    float* __restrict__ out)                   // (B,S,H,128) f32
{
    const int bid = blockIdx.x;
    int qt, c;
    if (bid < 256) { qt = 15 - (bid >> 5); c = bid & 31; }
    else           { qt = (bid - 256) >> 5; c = bid & 31; }
    const int h = c & 15, b = c >> 4;
    const int t = threadIdx.x, w = t >> 6, lane = t & 63;
    const int n16 = lane & 15, quad = lane >> 4;

    __shared__ unsigned short Kn[64 * 128];
    __shared__ unsigned short Kp[64 * 64];
    __shared__ unsigned short Vt[128 * 64];
    __shared__ unsigned short Ps[4][32 * 72];

    const unsigned short* knb = knope + (size_t)b * 2048 * 2048 + h * 128;
    const unsigned short* kpb = kpe + (size_t)b * 2048 * 64;
    const unsigned short* vtb = vT + (size_t)(b * 16 + h) * 128 * 2048;

    // Q fragments: wave w owns rows qt*128 + w*32 + mt*16 + n16
    short8 qf[2][6];
    for (int mt = 0; mt < 2; mt++) {
        size_t grow = (size_t)(b * SS + qt * 128 + w * 32 + mt * 16 + n16);
        const unsigned short* qp = qbuf + grow * (HH * QD) + h * QD + quad * 8;
        for (int ks = 0; ks < 6; ks++) qf[mt][ks] = *(const short8*)(qp + ks * 32);
    }

    f32x4 O[2][8] = {};
    float m_i[2][4], ps[2][4];
    for (int mt = 0; mt < 2; mt++)
        for (int r = 0; r < 4; r++) { m_i[mt][r] = -INFINITY; ps[mt][r] = 0.f; }

    const int nkt = 2 * qt + 2;
    for (int kt = 0; kt < nkt; kt++) {
        __syncthreads();
        {   // K nope: 64 keys x 128 shorts; 4 glds x 4 rows
            int r = w * 16 + (lane >> 4);
            int sl = lane & 15;
            for (int j = 0; j < 4; j++) {
                int rr = r + j * 4;
                const unsigned short* g = knb + (size_t)(kt * 64 + rr) * 2048 + ((sl ^ (rr & 7)) * 8);
                GLDS16(g, &Kn[(w * 16 + j * 4) * 128]);
            }
        }
        {   // K pe: 64 keys x 64 shorts; 2 glds x 8 rows
            int r = w * 16 + (lane >> 3);
            int sl = lane & 7;
            for (int j = 0; j < 2; j++) {
                int rr = r + j * 8;
                const unsigned short* g = kpb + (size_t)(kt * 64 + rr) * 64 + ((sl ^ (rr & 7)) * 8);
                GLDS16(g, &Kp[(w * 16 + j * 8) * 64]);
            }
        }
        {   // V^T: 128 vd x 64 keys; 4 glds x 8 rows
            int r = w * 32 + (lane >> 3);
            int sl = lane & 7;
            for (int j = 0; j < 4; j++) {
                int rr = r + j * 8;
                const unsigned short* g = vtb + (size_t)rr * 2048 + kt * 64 + ((sl ^ (rr & 7)) * 8);
                GLDS16(g, &Vt[(w * 32 + j * 8) * 64]);
            }
        }
        __syncthreads();

        // QK^T: B-frags read once, feed both m-frags
        f32x4 Sg[2][4];
        for (int nt = 0; nt < 4; nt++) {
            int key = nt * 16 + n16, kx = key & 7;
            f32x4 a0 = {}, a1 = {};
            for (int ks = 0; ks < 4; ks++) {
                short8 bfr = *(const short8*)&Kn[key * 128 + (((ks * 4 + quad) ^ kx) * 8)];
                a0 = __builtin_amdgcn_mfma_f32_16x16x32_bf16(qf[0][ks], bfr, a0, 0, 0, 0);
                a1 = __builtin_amdgcn_mfma_f32_16x16x32_bf16(qf[1][ks], bfr, a1, 0, 0, 0);
            }
            for (int ks = 0; ks < 2; ks++) {
                short8 bfr = *(const short8*)&Kp[key * 64 + (((ks * 4 + quad) ^ kx) * 8)];
                a0 = __builtin_amdgcn_mfma_f32_16x16x32_bf16(qf[0][4 + ks], bfr, a0, 0, 0, 0);
                a1 = __builtin_amdgcn_mfma_f32_16x16x32_bf16(qf[1][4 + ks], bfr, a1, 0, 0, 0);
            }
            Sg[0][nt] = a0; Sg[1][nt] = a1;
        }

        const bool edge = (kt >= 2 * qt);
        for (int mt = 0; mt < 2; mt++) {
            if (edge) {
                int rowg = qt * 128 + w * 32 + mt * 16 + quad * 4;
                for (int nt = 0; nt < 4; nt++) {
                    int colg = kt * 64 + nt * 16 + n16;
                    for (int r = 0; r < 4; r++)
                        if (colg > rowg + r) Sg[mt][nt][r] = -INFINITY;
                }
            }
            // online softmax (base 2), DPP reductions, deferred l
            for (int r = 0; r < 4; r++) {
                float mx = fmaxf(fmaxf(Sg[mt][0][r], Sg[mt][1][r]),
                                 fmaxf(Sg[mt][2][r], Sg[mt][3][r]));
                mx = rowmax16(mx);
                float mnew = fmaxf(m_i[mt][r], mx);
                float alpha = exp2f(m_i[mt][r] - mnew);
                m_i[mt][r] = mnew;
                float rs = 0.f;
                for (int nt = 0; nt < 4; nt++) {
                    float pv = exp2f(Sg[mt][nt][r] - mnew);
                    Sg[mt][nt][r] = pv;
                    rs += pv;
                }
                ps[mt][r] = ps[mt][r] * alpha + rs;   // per-lane partial; reduce at end
                for (int v8 = 0; v8 < 8; v8++) O[mt][v8][r] *= alpha;
            }
            // P -> per-wave LDS (wave-internal RAW)
            for (int nt = 0; nt < 4; nt++)
                for (int r = 0; r < 4; r++)
                    Ps[w][(mt * 16 + quad * 4 + r) * 72 + nt * 16 + n16] = f2bf(Sg[mt][nt][r]);
        }
        // PV for both m-frags, V-frags shared
        for (int ks = 0; ks < 2; ks++) {
            short8 pa0 = *(const short8*)&Ps[w][(0 + n16) * 72 + ks * 32 + quad * 8];
            short8 pa1 = *(const short8*)&Ps[w][(16 + n16) * 72 + ks * 32 + quad * 8];
            for (int v8 = 0; v8 < 8; v8++) {
                int vd = v8 * 16 + n16;
                short8 vb = *(const short8*)&Vt[vd * 64 + (((ks * 4 + quad) ^ (vd & 7)) * 8)];
                O[0][v8] = __builtin_amdgcn_mfma_f32_16x16x32_bf16(pa0, vb, O[0][v8], 0, 0, 0);
                O[1][v8] = __builtin_amdgcn_mfma_f32_16x16x32_bf16(pa1, vb, O[1][v8], 0, 0, 0);
            }
        }
    }

    // epilogue: DPP-reduce l across the 16-lane row group, write out
    for (int mt = 0; mt < 2; mt++)
        for (int r = 0; r < 4; r++) {
            float inv = 1.f / rowsum16(ps[mt][r]);
            size_t qrow = (size_t)(b * SS + qt * 128 + w * 32 + mt * 16 + quad * 4 + r);
            float* op = out + (qrow * HH + h) * VDIM;
            for (int v8 = 0; v8 < 8; v8++)
                op[v8 * 16 + n16] = O[mt][v8][r] * inv;
        }
}

extern "C" void kernel_launch(void* const* d_in, const int* in_sizes, int n_in,
                              void* d_out, int out_size, void* d_ws, size_t ws_size,
                              hipStream_t stream) {
    const float* Q    = (const float*)d_in[0];
    const float* KV   = (const float*)d_in[1];
    const float* PE   = (const float*)d_in[2];
    const float* WUQ  = (const float*)d_in[3];
    const float* WUKV = (const float*)d_in[4];
    const float* cosp = (const float*)d_in[5];
    const float* sinp = (const float*)d_in[6];
    float* out = (float*)d_out;

    unsigned short* qbuf  = (unsigned short*)d_ws;                 // 4096x3072
    unsigned short* knope = qbuf  + (size_t)4096 * 3072;           // 4096x2048
    unsigned short* vT    = knope + (size_t)4096 * 2048;           // 4096x2048
    unsigned short* kpe   = vT    + (size_t)4096 * 2048;           // 4096x64
    unsigned short* Qb    = kpe   + (size_t)4096 * 64;             // 4096x1536
    unsigned short* WUQb  = Qb    + (size_t)4096 * 1536;           // 3072x1536
    unsigned short* KVb   = WUQb  + (size_t)3072 * 1536;           // 4096x512
    unsigned short* WUKVb = KVb   + (size_t)4096 * 512;            // 4096x512

    cvt_all<<<15360, 256, 0, stream>>>(Q, WUQ, KV, WUKV, PE, cosp, sinp,
                                       Qb, WUQb, KVb, WUKVb, kpe);
    // q = Q @ WUQ^T (pre-scaled) + fused rope on pe cols
    gemm_bf16<false, true><<<dim3(24, 32), 256, 0, stream>>>(
        Qb, WUQb, qbuf, nullptr, cosp, sinp, 4096, 3072, 1536);
    // kv = KV @ WUKV^T, split epilogue (knope + vT)
    gemm_bf16<true, false><<<dim3(32, 32), 256, 0, stream>>>(
        KVb, WUKVb, knope, vT, nullptr, nullptr, 4096, 4096, 512);
    attn_kernel<<<512, 256, 0, stream>>>(qbuf, knope, kpe, vT, out);
}

// Round 5
// 302.327 us; speedup vs baseline: 1.8193x; 1.1207x over previous
//
#include <hip/hip_runtime.h>

typedef __attribute__((ext_vector_type(8))) short short8;
typedef __attribute__((ext_vector_type(4))) float f32x4;

#define SS 2048
#define HH 16
#define NOPE_D 128
#define ROPE_D 64
#define VDIM 128
#define QD 192
#define SCALE_F 0.07216878364870323f       // 1/sqrt(192)
#define LOG2E 1.4426950408889634f

__device__ __forceinline__ unsigned short f2bf(float f) {
    unsigned int x = __builtin_bit_cast(unsigned int, f);
    unsigned int r = (x + 0x7fffu + ((x >> 16) & 1u)) >> 16;
    return (unsigned short)r;
}

#define GLDS16(g, l) __builtin_amdgcn_global_load_lds( \
    (const __attribute__((address_space(1))) void*)(g), \
    (__attribute__((address_space(3))) void*)(l), 16, 0, 0)

// ------- fused f32->bf16 convert (4 arrays) + rope_k, one launch -------
__global__ __launch_bounds__(256) void cvt_all(
    const float* __restrict__ Q, const float* __restrict__ WUQ,
    const float* __restrict__ KV, const float* __restrict__ WUKV,
    const float* __restrict__ PE, const float* __restrict__ cs, const float* __restrict__ sn,
    unsigned short* __restrict__ Qb, unsigned short* __restrict__ WUQb,
    unsigned short* __restrict__ KVb, unsigned short* __restrict__ WUKVb,
    unsigned short* __restrict__ kpe)
{
    int bid = blockIdx.x;
    if (bid >= 14848) {   // rope_k: PE (4096x64) -> kpe bf16
        int idx = (bid - 14848) * 256 + threadIdx.x;
        int i = idx & 31, row = idx >> 5;
        float x1 = PE[row * 64 + i], x2 = PE[row * 64 + 32 + i];
        float c1 = cs[row * 64 + i],      s1 = sn[row * 64 + i];
        float c2 = cs[row * 64 + 32 + i], s2 = sn[row * 64 + 32 + i];
        kpe[row * 64 + i]      = f2bf(x1 * c1 - x2 * s1);
        kpe[row * 64 + 32 + i] = f2bf(x2 * c2 + x1 * s2);
        return;
    }
    const float* src; unsigned short* dst; float scale = 1.0f;
    if (bid < 6144)       { src = Q;    dst = Qb; }
    else if (bid < 10752) { src = WUQ;  dst = WUQb; bid -= 6144; scale = SCALE_F * LOG2E; }
    else if (bid < 12800) { src = KV;   dst = KVb;  bid -= 10752; }
    else                  { src = WUKV; dst = WUKVb; bid -= 12800; }
    int i = (bid * 256 + threadIdx.x) * 4;
    float4 v = *(const float4*)(src + i);
    ushort4 o = { f2bf(v.x * scale), f2bf(v.y * scale), f2bf(v.z * scale), f2bf(v.w * scale) };
    *(ushort4*)(dst + i) = o;
}

// ------- fused GEMM1+GEMM2, 128x128 tile, BK=64, XOR-swizzled LDS -------
// blocks [0,768): q = Qb@WUQb^T (M4096,N3072,K1536) + in-register rope on pe cols
// blocks [768,1792): kv = KVb@WUKVb^T (M4096,N4096,K512), split epilogue:
//   k_nope -> knope[row][h*128+d];  v -> vT[(b,h,vd)][pi(s)] (key-permuted for attn PV)
__global__ __launch_bounds__(256) void gemm_fused(
    const unsigned short* __restrict__ Qb, const unsigned short* __restrict__ WUQb,
    const unsigned short* __restrict__ KVb, const unsigned short* __restrict__ WUKVb,
    unsigned short* __restrict__ qbuf, unsigned short* __restrict__ knope,
    unsigned short* __restrict__ vT,
    const float* __restrict__ cs, const float* __restrict__ sn)
{
    __shared__ unsigned short As[128 * 64];
    __shared__ unsigned short Bs[128 * 64];
    const int t = threadIdx.x, w = t >> 6, lane = t & 63;
    const int n16 = lane & 15, quad = lane >> 4;

    int bid = blockIdx.x;
    const unsigned short *A, *B; int N, K, bm, bn; bool g1;
    if (bid < 768) { g1 = true;  A = Qb;  B = WUQb;  N = 3072; K = 1536;
                     bm = (bid / 24) * 128; bn = (bid % 24) * 128; }
    else           { g1 = false; bid -= 768; A = KVb; B = WUKVb; N = 4096; K = 512;
                     bm = (bid / 32) * 128; bn = (bid % 32) * 128; }

    const int wm = (w >> 1) * 64, wn = (w & 1) * 64;
    f32x4 acc[4][4] = {};

    const int lr = lane >> 3, lc = lane & 7;
    const int sw = (lc ^ lr) * 8;           // swizzled source chunk
    const unsigned short* gA = A + (size_t)(bm + w * 32 + lr) * K + sw;
    const unsigned short* gB = B + (size_t)(bn + w * 32 + lr) * K + sw;

    for (int k0 = 0; k0 < K; k0 += 64) {
        __syncthreads();
        for (int j = 0; j < 4; j++) {
            GLDS16(gA + (size_t)j * 8 * K + k0, &As[(w * 32 + j * 8) * 64]);
            GLDS16(gB + (size_t)j * 8 * K + k0, &Bs[(w * 32 + j * 8) * 64]);
        }
        __syncthreads();
        for (int ks = 0; ks < 2; ks++) {
            short8 af[4], bf[4];
            for (int mt = 0; mt < 4; mt++) {
                int rw = wm + mt * 16 + n16;
                af[mt] = *(const short8*)&As[rw * 64 + (((ks * 4 + quad) ^ (rw & 7)) * 8)];
            }
            for (int nt = 0; nt < 4; nt++) {
                int rw = wn + nt * 16 + n16;
                bf[nt] = *(const short8*)&Bs[rw * 64 + (((ks * 4 + quad) ^ (rw & 7)) * 8)];
            }
            for (int mt = 0; mt < 4; mt++)
                for (int nt = 0; nt < 4; nt++)
                    acc[mt][nt] = __builtin_amdgcn_mfma_f32_16x16x32_bf16(af[mt], bf[nt], acc[mt][nt], 0, 0, 0);
        }
    }

    const int colbase = bn + wn;
    if (g1) {
        const bool is_pe = ((colbase % 192) >= 128);
        if (is_pe) {
            for (int mt = 0; mt < 4; mt++)
                for (int r = 0; r < 4; r++) {
                    int row = bm + wm + mt * 16 + quad * 4 + r;
                    const float* cr = cs + row * 64;
                    const float* sr = sn + row * 64;
                    for (int nt = 0; nt < 2; nt++) {
                        int i = nt * 16 + n16;
                        float x1 = acc[mt][nt][r], x2 = acc[mt][nt + 2][r];
                        float o1 = x1 * cr[i] - x2 * sr[i];
                        float o2 = x2 * cr[32 + i] + x1 * sr[32 + i];
                        qbuf[(size_t)row * N + colbase + i] = f2bf(o1);
                        qbuf[(size_t)row * N + colbase + 32 + i] = f2bf(o2);
                    }
                }
        } else {
            for (int mt = 0; mt < 4; mt++)
                for (int nt = 0; nt < 4; nt++)
                    for (int r = 0; r < 4; r++)
                        qbuf[(size_t)(bm + wm + mt * 16 + quad * 4 + r) * N + colbase + nt * 16 + n16]
                            = f2bf(acc[mt][nt][r]);
        }
    } else {
        if ((colbase & 255) < 128) {
            for (int mt = 0; mt < 4; mt++)
                for (int nt = 0; nt < 4; nt++) {
                    int col = colbase + nt * 16 + n16;
                    int h = col >> 8, d = col & 255;
                    for (int r = 0; r < 4; r++)
                        knope[(size_t)(bm + wm + mt * 16 + quad * 4 + r) * 2048 + h * 128 + d]
                            = f2bf(acc[mt][nt][r]);
                }
        } else {
            for (int mt = 0; mt < 4; mt++)
                for (int nt = 0; nt < 4; nt++) {
                    int col = colbase + nt * 16 + n16;
                    int h = col >> 8, vd = (col & 255) - 128;
                    int row0 = bm + wm + mt * 16 + quad * 4;
                    int b = row0 >> 11, s0 = row0 & 2047;
                    // key permutation pi within 64-groups (PV A/B pairing order)
                    int l6 = s0 & 63;
                    int scol = (s0 & ~63) + ((l6 >> 5) & 1) * 32 + ((l6 >> 2) & 3) * 8
                             + ((l6 >> 4) & 1) * 4 + (l6 & 3);
                    ushort4 pk = { f2bf(acc[mt][nt][0]), f2bf(acc[mt][nt][1]),
                                   f2bf(acc[mt][nt][2]), f2bf(acc[mt][nt][3]) };
                    *(ushort4*)&vT[((size_t)(b * 16 + h) * 128 + vd) * 2048 + scol] = pk;
                }
        }
    }
}

// ------- flash attention, causal, BQ=128, transposed-S / register-P path -------
// Dynamic work queue: 512 units (qt longest-first), 512 blocks pull via atomic.
// S^T = MFMA(A=K, B=Q): lane holds (key=nt*16+quad*4+r, q=qg*16+n16).
// PV: P packed to bf16 in-register as 16x16x32 A-frags (V key-permuted by pi).
__global__ __launch_bounds__(256, 2) void attn_kernel(
    const unsigned short* __restrict__ qbuf,   // (4096, 3072) roped, pre-scaled
    const unsigned short* __restrict__ knope,  // (4096, 2048): [row][h*128+d]
    const unsigned short* __restrict__ kpe,    // (4096, 64) roped
    const unsigned short* __restrict__ vT,     // [(b*16+h)*128+vd][pi(s)]
    float* __restrict__ out,                   // (B,S,H,128) f32
    int* __restrict__ qc)
{
    const int t = threadIdx.x, w = t >> 6, lane = t & 63;
    const int n16 = lane & 15, quad = lane >> 4;

    __shared__ unsigned short Kn[64 * 128];
    __shared__ unsigned short Kp[64 * 64];
    __shared__ unsigned short Vt[128 * 64];
    __shared__ float Al[4][32];
    __shared__ int su;

    while (true) {
        __syncthreads();
        if (t == 0) su = atomicAdd(qc, 1);
        __syncthreads();
        const int u = su;
        if (u >= 512) break;
        const int qt = 15 - (u >> 5);
        const int c = u & 31;
        const int h = c & 15, b = c >> 4;

        const unsigned short* knb = knope + (size_t)b * 2048 * 2048 + h * 128;
        const unsigned short* kpb = kpe + (size_t)b * 2048 * 64;
        const unsigned short* vtb = vT + (size_t)(b * 16 + h) * 128 * 2048;

        // Q as B-frags: wave w covers q rows qt*128 + w*32 + qg*16 + n16
        short8 qf[2][6];
        for (int qg = 0; qg < 2; qg++) {
            size_t grow = (size_t)(b * SS + qt * 128 + w * 32 + qg * 16 + n16);
            const unsigned short* qp = qbuf + grow * (HH * QD) + h * QD + quad * 8;
            for (int ks = 0; ks < 6; ks++) qf[qg][ks] = *(const short8*)(qp + ks * 32);
        }

        f32x4 O[2][8] = {};
        float m_i[2] = { -INFINITY, -INFINITY };
        float l_i[2] = { 0.f, 0.f };

        const int nkt = 2 * qt + 2;
        for (int kt = 0; kt < nkt; kt++) {
            __syncthreads();
            {   // K nope: 64 keys x 128 shorts; 4 glds x 4 rows, XOR swizzle
                int r = w * 16 + (lane >> 4);
                int sl = lane & 15;
                for (int j = 0; j < 4; j++) {
                    int rr = r + j * 4;
                    const unsigned short* g = knb + (size_t)(kt * 64 + rr) * 2048 + ((sl ^ (rr & 7)) * 8);
                    GLDS16(g, &Kn[(w * 16 + j * 4) * 128]);
                }
            }
            {   // K pe: 64 keys x 64 shorts; 2 glds x 8 rows
                int r = w * 16 + (lane >> 3);
                int sl = lane & 7;
                for (int j = 0; j < 2; j++) {
                    int rr = r + j * 8;
                    const unsigned short* g = kpb + (size_t)(kt * 64 + rr) * 64 + ((sl ^ (rr & 7)) * 8);
                    GLDS16(g, &Kp[(w * 16 + j * 8) * 64]);
                }
            }
            {   // V^T: 128 vd x 64 keys (key-permuted); 4 glds x 8 rows
                int r = w * 32 + (lane >> 3);
                int sl = lane & 7;
                for (int j = 0; j < 4; j++) {
                    int rr = r + j * 8;
                    const unsigned short* g = vtb + (size_t)rr * 2048 + kt * 64 + ((sl ^ (rr & 7)) * 8);
                    GLDS16(g, &Vt[(w * 32 + j * 8) * 64]);
                }
            }
            __syncthreads();

            // S^T[key][q]: A = K-frags (LDS, shared across qg), B = Q (regs)
            f32x4 Sg[2][4];
            for (int nt = 0; nt < 4; nt++) {
                int key = nt * 16 + n16, kx = key & 7;
                f32x4 a0 = {}, a1 = {};
                for (int ks = 0; ks < 4; ks++) {
                    short8 af = *(const short8*)&Kn[key * 128 + (((ks * 4 + quad) ^ kx) * 8)];
                    a0 = __builtin_amdgcn_mfma_f32_16x16x32_bf16(af, qf[0][ks], a0, 0, 0, 0);
                    a1 = __builtin_amdgcn_mfma_f32_16x16x32_bf16(af, qf[1][ks], a1, 0, 0, 0);
                }
                for (int ks = 0; ks < 2; ks++) {
                    short8 af = *(const short8*)&Kp[key * 64 + (((ks * 4 + quad) ^ kx) * 8)];
                    a0 = __builtin_amdgcn_mfma_f32_16x16x32_bf16(af, qf[0][4 + ks], a0, 0, 0, 0);
                    a1 = __builtin_amdgcn_mfma_f32_16x16x32_bf16(af, qf[1][4 + ks], a1, 0, 0, 0);
                }
                Sg[0][nt] = a0; Sg[1][nt] = a1;
            }

            if (kt >= 2 * qt) {   // causal mask on the last two k-tiles
                for (int qg = 0; qg < 2; qg++) {
                    int qq = qt * 128 + w * 32 + qg * 16 + n16;
                    for (int nt = 0; nt < 4; nt++) {
                        int key0 = kt * 64 + nt * 16 + quad * 4;
                        for (int r = 0; r < 4; r++)
                            if (key0 + r > qq) Sg[qg][nt][r] = -INFINITY;
                    }
                }
            }

            // online softmax (base 2) in S^T domain; reduction over keys =
            // in-lane 16 + across quads (shfl_xor 16,32)
            float alpha[2];
            for (int qg = 0; qg < 2; qg++) {
                float mx = -INFINITY;
                for (int nt = 0; nt < 4; nt++)
                    for (int r = 0; r < 4; r++) mx = fmaxf(mx, Sg[qg][nt][r]);
                mx = fmaxf(mx, __shfl_xor(mx, 16, 64));
                mx = fmaxf(mx, __shfl_xor(mx, 32, 64));
                float mnew = fmaxf(m_i[qg], mx);
                alpha[qg] = exp2f(m_i[qg] - mnew);
                m_i[qg] = mnew;
                float rs = 0.f;
                for (int nt = 0; nt < 4; nt++)
                    for (int r = 0; r < 4; r++) {
                        float pv = exp2f(Sg[qg][nt][r] - mnew);
                        Sg[qg][nt][r] = pv;
                        rs += pv;
                    }
                l_i[qg] = l_i[qg] * alpha[qg] + rs;   // per-lane partial (quad-split)
            }
            // broadcast alpha (S^T q=n16 domain) to O lanes (q=quad*4+r domain)
            if (quad == 0) { Al[w][n16] = alpha[0]; Al[w][16 + n16] = alpha[1]; }
            f32x4 av0 = *(const f32x4*)&Al[w][quad * 4];
            f32x4 av1 = *(const f32x4*)&Al[w][16 + quad * 4];
            for (int v8 = 0; v8 < 8; v8++)
                for (int r = 0; r < 4; r++) {
                    O[0][v8][r] *= av0[r];
                    O[1][v8][r] *= av1[r];
                }

            // pack P to bf16 A-frags (k order matches pi-permuted V columns)
            short8 pp[2][2];
            for (int qg = 0; qg < 2; qg++)
                for (int ntp = 0; ntp < 2; ntp++) {
                    short8 pa;
                    for (int j = 0; j < 4; j++) pa[j] = (short)f2bf(Sg[qg][ntp * 2][j]);
                    for (int j = 0; j < 4; j++) pa[4 + j] = (short)f2bf(Sg[qg][ntp * 2 + 1][j]);
                    pp[qg][ntp] = pa;
                }
            // PV: O[q][vd] += P * V, B-frags shared across qg
            for (int ntp = 0; ntp < 2; ntp++)
                for (int v8 = 0; v8 < 8; v8++) {
                    int vd = v8 * 16 + n16;
                    short8 vb = *(const short8*)&Vt[vd * 64 + (((ntp * 4 + quad) ^ (vd & 7)) * 8)];
                    O[0][v8] = __builtin_amdgcn_mfma_f32_16x16x32_bf16(pp[0][ntp], vb, O[0][v8], 0, 0, 0);
                    O[1][v8] = __builtin_amdgcn_mfma_f32_16x16x32_bf16(pp[1][ntp], vb, O[1][v8], 0, 0, 0);
                }
        }

        // epilogue: total l (reduce across quads), broadcast 1/l to O lanes
        {
            float l0 = l_i[0];
            l0 += __shfl_xor(l0, 16, 64); l0 += __shfl_xor(l0, 32, 64);
            float l1 = l_i[1];
            l1 += __shfl_xor(l1, 16, 64); l1 += __shfl_xor(l1, 32, 64);
            if (quad == 0) { Al[w][n16] = 1.f / l0; Al[w][16 + n16] = 1.f / l1; }
        }
        f32x4 lv0 = *(const f32x4*)&Al[w][quad * 4];
        f32x4 lv1 = *(const f32x4*)&Al[w][16 + quad * 4];
        for (int qg = 0; qg < 2; qg++) {
            const f32x4 lv = qg ? lv1 : lv0;
            for (int r = 0; r < 4; r++) {
                size_t qrow = (size_t)(b * SS + qt * 128 + w * 32 + qg * 16 + quad * 4 + r);
                float* op = out + (qrow * HH + h) * VDIM;
                for (int v8 = 0; v8 < 8; v8++)
                    op[v8 * 16 + n16] = O[qg][v8][r] * lv[r];
            }
        }
    }
}

extern "C" void kernel_launch(void* const* d_in, const int* in_sizes, int n_in,
                              void* d_out, int out_size, void* d_ws, size_t ws_size,
                              hipStream_t stream) {
    const float* Q    = (const float*)d_in[0];
    const float* KV   = (const float*)d_in[1];
    const float* PE   = (const float*)d_in[2];
    const float* WUQ  = (const float*)d_in[3];
    const float* WUKV = (const float*)d_in[4];
    const float* cosp = (const float*)d_in[5];
    const float* sinp = (const float*)d_in[6];
    float* out = (float*)d_out;

    unsigned short* qbuf  = (unsigned short*)d_ws;                 // 4096x3072
    unsigned short* knope = qbuf  + (size_t)4096 * 3072;           // 4096x2048
    unsigned short* vT    = knope + (size_t)4096 * 2048;           // 4096x2048 (pi-permuted)
    unsigned short* kpe   = vT    + (size_t)4096 * 2048;           // 4096x64
    unsigned short* Qb    = kpe   + (size_t)4096 * 64;             // 4096x1536
    unsigned short* WUQb  = Qb    + (size_t)4096 * 1536;           // 3072x1536
    unsigned short* KVb   = WUQb  + (size_t)3072 * 1536;           // 4096x512
    unsigned short* WUKVb = KVb   + (size_t)4096 * 512;            // 4096x512
    int* qcounter = (int*)(WUKVb + (size_t)4096 * 512);            // work queue

    hipMemsetAsync(qcounter, 0, 4, stream);
    cvt_all<<<15360, 256, 0, stream>>>(Q, WUQ, KV, WUKV, PE, cosp, sinp,
                                       Qb, WUQb, KVb, WUKVb, kpe);
    gemm_fused<<<1792, 256, 0, stream>>>(Qb, WUQb, KVb, WUKVb,
                                         qbuf, knope, vT, cosp, sinp);
    attn_kernel<<<512, 256, 0, stream>>>(qbuf, knope, kpe, vT, out, qcounter);
}